// Round 1
// baseline (1496.064 us; speedup 1.0000x reference)
//
#include <hip/hip_runtime.h>

// Problem constants
constexpr int N_NODES = 50000;
constexpr int E_EDGES = 800000;
constexpr int EA      = E_EDGES + N_NODES;  // edges + self loops = 850000
constexpr int IN_DIM  = 128;
constexpr int HID     = 64;
constexpr int HEADS   = 4;
constexpr int HH      = HEADS * HID;        // 256
constexpr int EDGE_DIM = 8;
constexpr int L_LAYERS = 2;
constexpr float NEG_SLOPE = 0.2f;

__device__ __forceinline__ unsigned int enc_f32(float f) {
    unsigned int b = __float_as_uint(f);
    return (b & 0x80000000u) ? ~b : (b | 0x80000000u);
}
__device__ __forceinline__ float dec_f32(unsigned int u) {
    unsigned int b = (u & 0x80000000u) ? (u & 0x7FFFFFFFu) : ~u;
    return __uint_as_float(b);
}

// ---------------- Kernel 1: x = x_in @ proj_w + proj_b ----------------
__global__ void proj_kernel(const float* __restrict__ x, const float* __restrict__ w,
                            const float* __restrict__ b, float* __restrict__ out) {
    int base_row = blockIdx.x * 4;
    int row = base_row + (threadIdx.x >> 6);
    int c = threadIdx.x & 63;
    __shared__ float xs[4][IN_DIM];
    for (int i = threadIdx.x; i < 4 * IN_DIM; i += 256) {
        int r = i >> 7, k = i & 127;
        int gr = base_row + r;
        xs[r][k] = (gr < N_NODES) ? x[gr * IN_DIM + k] : 0.f;
    }
    __syncthreads();
    if (row >= N_NODES) return;
    const float* xr = xs[threadIdx.x >> 6];
    float acc = b[c];
#pragma unroll 8
    for (int k = 0; k < IN_DIM; ++k) acc += xr[k] * w[k * HID + c];
    out[row * HID + c] = acc;
}

// ---------------- Kernel 2: histogram of edge_attr -------------------
__global__ void count_attr_kernel(const int* __restrict__ attr, int* __restrict__ counts) {
    int c0 = 0, c1 = 0, c2 = 0;
    for (int i = blockIdx.x * blockDim.x + threadIdx.x; i < E_EDGES; i += gridDim.x * blockDim.x) {
        int a = attr[i];
        c0 += (a == 0); c1 += (a == 1); c2 += (a == 2);
    }
    for (int o = 32; o; o >>= 1) {
        c0 += __shfl_down(c0, o);
        c1 += __shfl_down(c1, o);
        c2 += __shfl_down(c2, o);
    }
    if ((threadIdx.x & 63) == 0) {
        atomicAdd(&counts[0], c0);
        atomicAdd(&counts[1], c1);
        atomicAdd(&counts[2], c2);
    }
}

// ---------------- Kernel 3: eet[t][hc] = edge-type transform ---------
// t in {0,1,2}: edge_emb[t] @ We ; t==3: mean edge feature @ We
__global__ void eet_kernel(const float* __restrict__ edge_emb, const float* __restrict__ We_l,
                           const int* __restrict__ counts, float* __restrict__ eet) {
    int hc = threadIdx.x;  // 256
    float inv = 1.f / (float)E_EDGES;
    for (int t = 0; t < 3; ++t) {
        float acc = 0.f;
#pragma unroll
        for (int d = 0; d < EDGE_DIM; ++d) acc += edge_emb[t * EDGE_DIM + d] * We_l[d * HH + hc];
        eet[t * HH + hc] = acc;
    }
    float acc = 0.f;
#pragma unroll
    for (int d = 0; d < EDGE_DIM; ++d) {
        float md = (counts[0] * edge_emb[0 * EDGE_DIM + d] +
                    counts[1] * edge_emb[1 * EDGE_DIM + d] +
                    counts[2] * edge_emb[2 * EDGE_DIM + d]) * inv;
        acc += md * We_l[d * HH + hc];
    }
    eet[3 * HH + hc] = acc;
}

// ---------------- Kernel 4: xl = x@Wl, xr = x@Wr ---------------------
__global__ void transform_kernel(const float* __restrict__ x, const float* __restrict__ Wl,
                                 const float* __restrict__ Wr, float* __restrict__ xl,
                                 float* __restrict__ xr) {
    int n = blockIdx.x;
    int hc = threadIdx.x;  // 256
    __shared__ float xs[HID];
    if (threadIdx.x < HID) xs[threadIdx.x] = x[n * HID + threadIdx.x];
    __syncthreads();
    float al = 0.f, ar = 0.f;
#pragma unroll 8
    for (int k = 0; k < HID; ++k) {
        float xv = xs[k];
        al += xv * Wl[k * HH + hc];
        ar += xv * Wr[k * HH + hc];
    }
    xl[(size_t)n * HH + hc] = al;
    xr[(size_t)n * HH + hc] = ar;
}

// ---------------- Kernel 5: per-edge attention score + segment max ---
__global__ void score_kernel(const int* __restrict__ src_idx, const int* __restrict__ dst_idx,
                             const int* __restrict__ attr, const float* __restrict__ xl,
                             const float* __restrict__ xr, const float* __restrict__ eet,
                             const float* __restrict__ att_l, float* __restrict__ s_out,
                             unsigned int* __restrict__ smax) {
    int e = blockIdx.x * 4 + (threadIdx.x >> 6);
    if (e >= EA) return;
    int lane = threadIdx.x & 63;
    int srcn, dstn, t;
    if (e < E_EDGES) { srcn = src_idx[e]; dstn = dst_idx[e]; t = attr[e]; }
    else             { srcn = e - E_EDGES; dstn = srcn; t = 3; }
    const float4* xlp = (const float4*)(xl + (size_t)srcn * HH);
    const float4* xrp = (const float4*)(xr + (size_t)dstn * HH);
    const float4* eep = (const float4*)(eet + t * HH);
    const float4* ap  = (const float4*)att_l;
    float4 xv = xlp[lane], rv = xrp[lane], ev = eep[lane], av = ap[lane];
    float m0 = xv.x + rv.x + ev.x;
    float m1 = xv.y + rv.y + ev.y;
    float m2 = xv.z + rv.z + ev.z;
    float m3 = xv.w + rv.w + ev.w;
    m0 = (m0 >= 0.f) ? m0 : NEG_SLOPE * m0;
    m1 = (m1 >= 0.f) ? m1 : NEG_SLOPE * m1;
    m2 = (m2 >= 0.f) ? m2 : NEG_SLOPE * m2;
    m3 = (m3 >= 0.f) ? m3 : NEG_SLOPE * m3;
    float p = m0 * av.x + m1 * av.y + m2 * av.z + m3 * av.w;
    // lanes 16h..16h+15 all belong to head h -> reduce within 16-lane groups
    for (int o = 1; o < 16; o <<= 1) p += __shfl_xor(p, o);
    if ((lane & 15) == 0) {
        int h = lane >> 4;
        s_out[(size_t)e * 4 + h] = p;
        atomicMax(&smax[dstn * 4 + h], enc_f32(p));
    }
}

// ---------------- Kernel 6: a = exp(s - max), denom = segsum ---------
__global__ void expdenom_kernel(const int* __restrict__ dst_idx, float* __restrict__ s_a,
                                const unsigned int* __restrict__ smax, float* __restrict__ denom) {
    int i = blockIdx.x * blockDim.x + threadIdx.x;
    if (i >= EA * 4) return;
    int e = i >> 2, h = i & 3;
    int dstn = (e < E_EDGES) ? dst_idx[e] : e - E_EDGES;
    float mx = dec_f32(smax[dstn * 4 + h]);
    float av = expf(s_a[i] - mx);
    s_a[i] = av;  // in-place: s -> a
    atomicAdd(&denom[dstn * 4 + h], av);
}

// ---------------- Kernel 7: out[dst] += mean_h alpha_h * xl[src,h,:] -
__global__ void aggregate_kernel(const int* __restrict__ src_idx, const int* __restrict__ dst_idx,
                                 const float* __restrict__ a, const float* __restrict__ denom,
                                 const float* __restrict__ xl, float* __restrict__ outacc) {
    int e = blockIdx.x * 4 + (threadIdx.x >> 6);
    if (e >= EA) return;
    int lane = threadIdx.x & 63;
    int srcn, dstn;
    if (e < E_EDGES) { srcn = src_idx[e]; dstn = dst_idx[e]; }
    else             { srcn = e - E_EDGES; dstn = srcn; }
    float al0 = a[(size_t)e * 4 + 0] / denom[dstn * 4 + 0];
    float al1 = a[(size_t)e * 4 + 1] / denom[dstn * 4 + 1];
    float al2 = a[(size_t)e * 4 + 2] / denom[dstn * 4 + 2];
    float al3 = a[(size_t)e * 4 + 3] / denom[dstn * 4 + 3];
    const float* xp = xl + (size_t)srcn * HH;
    float v = 0.25f * (al0 * xp[lane] + al1 * xp[64 + lane] +
                       al2 * xp[128 + lane] + al3 * xp[192 + lane]);
    atomicAdd(&outacc[(size_t)dstn * HID + lane], v);
}

// ---------------- Kernel 8: residual + LayerNorm ---------------------
__global__ void ln_kernel(const float* __restrict__ outacc, const float* __restrict__ bias_l,
                          const float* __restrict__ ln_w, const float* __restrict__ ln_b,
                          const float* __restrict__ x_in, float* __restrict__ x_out) {
    int n = blockIdx.x * 4 + (threadIdx.x >> 6);
    if (n >= N_NODES) return;
    int c = threadIdx.x & 63;
    float h = outacc[(size_t)n * HID + c] + bias_l[c] + x_in[(size_t)n * HID + c];
    float sum = h;
    for (int o = 32; o; o >>= 1) sum += __shfl_xor(sum, o);
    float mu = sum * (1.f / 64.f);
    float d = h - mu;
    float vs = d * d;
    for (int o = 32; o; o >>= 1) vs += __shfl_xor(vs, o);
    float var = vs * (1.f / 64.f);
    x_out[(size_t)n * HID + c] = d * rsqrtf(var + 1e-5f) * ln_w[c] + ln_b[c];
}

extern "C" void kernel_launch(void* const* d_in, const int* in_sizes, int n_in,
                              void* d_out, int out_size, void* d_ws, size_t ws_size,
                              hipStream_t stream) {
    const float* x_in     = (const float*)d_in[0];
    const int*   edge_idx = (const int*)d_in[1];   // [2, E]: row0 = src, row1 = dst
    const int*   attr     = (const int*)d_in[2];
    const float* proj_w   = (const float*)d_in[3];
    const float* proj_b   = (const float*)d_in[4];
    const float* edge_emb = (const float*)d_in[5];
    const float* Wl       = (const float*)d_in[6];
    const float* Wr       = (const float*)d_in[7];
    const float* We       = (const float*)d_in[8];
    const float* att      = (const float*)d_in[9];
    const float* bias     = (const float*)d_in[10];
    const float* ln_w     = (const float*)d_in[11];
    const float* ln_b     = (const float*)d_in[12];
    float* out = (float*)d_out;

    const int* src_idx = edge_idx;
    const int* dst_idx = edge_idx + E_EDGES;

    // Workspace layout (floats)
    float* ws = (float*)d_ws;
    float* x_cur  = ws;                        // N*HID        = 3.2M
    float* xl     = x_cur + (size_t)N_NODES * HID;     // N*HH = 12.8M
    float* xr     = xl + (size_t)N_NODES * HH;         // N*HH = 12.8M
    float* s_a    = xr + (size_t)N_NODES * HH;         // EA*4 = 3.4M
    float* outacc = s_a + (size_t)EA * 4;              // N*HID = 3.2M
    float* denom  = outacc + (size_t)N_NODES * HID;    // N*4
    unsigned int* smax = (unsigned int*)(denom + (size_t)N_NODES * 4);  // N*4
    float* eet    = (float*)(smax + (size_t)N_NODES * 4);               // 4*HH
    int*   counts = (int*)(eet + 4 * HH);                               // 4

    hipMemsetAsync(counts, 0, 4 * sizeof(int), stream);
    proj_kernel<<<(N_NODES + 3) / 4, 256, 0, stream>>>(x_in, proj_w, proj_b, x_cur);
    count_attr_kernel<<<256, 256, 0, stream>>>(attr, counts);

    for (int l = 0; l < L_LAYERS; ++l) {
        const float* Wl_l = Wl + (size_t)l * HID * HH;
        const float* Wr_l = Wr + (size_t)l * HID * HH;
        const float* We_l = We + (size_t)l * EDGE_DIM * HH;
        const float* att_l = att + (size_t)l * HH;
        const float* bias_l = bias + (size_t)l * HID;
        const float* lnw_l = ln_w + (size_t)l * HID;
        const float* lnb_l = ln_b + (size_t)l * HID;

        eet_kernel<<<1, 256, 0, stream>>>(edge_emb, We_l, counts, eet);
        transform_kernel<<<N_NODES, 256, 0, stream>>>(x_cur, Wl_l, Wr_l, xl, xr);

        hipMemsetAsync(smax, 0, (size_t)N_NODES * 4 * sizeof(unsigned int), stream);
        hipMemsetAsync(denom, 0, (size_t)N_NODES * 4 * sizeof(float), stream);
        hipMemsetAsync(outacc, 0, (size_t)N_NODES * HID * sizeof(float), stream);

        score_kernel<<<(EA + 3) / 4, 256, 0, stream>>>(src_idx, dst_idx, attr, xl, xr, eet,
                                                       att_l, s_a, smax);
        expdenom_kernel<<<(EA * 4 + 255) / 256, 256, 0, stream>>>(dst_idx, s_a, smax, denom);
        aggregate_kernel<<<(EA + 3) / 4, 256, 0, stream>>>(src_idx, dst_idx, s_a, denom, xl, outacc);

        float* x_next = (l == L_LAYERS - 1) ? out : x_cur;
        ln_kernel<<<(N_NODES + 3) / 4, 256, 0, stream>>>(outacc, bias_l, lnw_l, lnb_l, x_cur, x_next);
    }
}

// Round 2
// 978.951 us; speedup vs baseline: 1.5282x; 1.5282x over previous
//
#include <hip/hip_runtime.h>

// Problem constants
constexpr int N_NODES = 50000;
constexpr int E_EDGES = 800000;
constexpr int EA      = E_EDGES + N_NODES;  // edges + self loops = 850000
constexpr int IN_DIM  = 128;
constexpr int HID     = 64;
constexpr int HEADS   = 4;
constexpr int HH      = HEADS * HID;        // 256
constexpr int EDGE_DIM = 8;
constexpr int L_LAYERS = 2;
constexpr float NEG_SLOPE = 0.2f;

__device__ __forceinline__ unsigned short f2bf(float f) {
    unsigned int b = __float_as_uint(f);
    unsigned int r = (b + 0x7FFFu + ((b >> 16) & 1u)) >> 16;  // round-to-nearest-even
    return (unsigned short)r;
}
__device__ __forceinline__ float bf2f(unsigned short u) {
    return __uint_as_float(((unsigned int)u) << 16);
}

// ---------------- Kernel 1: x = x_in @ proj_w + proj_b ----------------
// 16 nodes per block; 256 threads = 64 cols x 4 node-groups (4 nodes/thread)
__global__ void proj_kernel(const float* __restrict__ x, const float* __restrict__ w,
                            const float* __restrict__ b, float* __restrict__ out) {
    int base = blockIdx.x * 16;
    int c = threadIdx.x & 63;
    int g = threadIdx.x >> 6;  // 0..3
    __shared__ float xs[16][IN_DIM];
    for (int i = threadIdx.x; i < 16 * IN_DIM; i += 256) {
        int r = i >> 7, k = i & 127;
        xs[r][k] = x[(size_t)(base + r) * IN_DIM + k];
    }
    __syncthreads();
    float acc[4];
    float bc = b[c];
#pragma unroll
    for (int j = 0; j < 4; ++j) acc[j] = bc;
    for (int k0 = 0; k0 < IN_DIM; k0 += 4) {
        float w0 = w[(k0 + 0) * HID + c];
        float w1 = w[(k0 + 1) * HID + c];
        float w2 = w[(k0 + 2) * HID + c];
        float w3 = w[(k0 + 3) * HID + c];
#pragma unroll
        for (int j = 0; j < 4; ++j) {
            float4 xv = *(const float4*)&xs[g + 4 * j][k0];
            acc[j] += xv.x * w0 + xv.y * w1 + xv.z * w2 + xv.w * w3;
        }
    }
#pragma unroll
    for (int j = 0; j < 4; ++j) out[(size_t)(base + g + 4 * j) * HID + c] = acc[j];
}

// ---------------- Kernel 2: histogram of edge_attr -------------------
__global__ void count_attr_kernel(const int* __restrict__ attr, int* __restrict__ counts) {
    int c0 = 0, c1 = 0, c2 = 0;
    for (int i = blockIdx.x * blockDim.x + threadIdx.x; i < E_EDGES; i += gridDim.x * blockDim.x) {
        int a = attr[i];
        c0 += (a == 0); c1 += (a == 1); c2 += (a == 2);
    }
    for (int o = 32; o; o >>= 1) {
        c0 += __shfl_down(c0, o);
        c1 += __shfl_down(c1, o);
        c2 += __shfl_down(c2, o);
    }
    if ((threadIdx.x & 63) == 0) {
        atomicAdd(&counts[0], c0);
        atomicAdd(&counts[1], c1);
        atomicAdd(&counts[2], c2);
    }
}

// ---------------- Kernel 3: eet[t][hc] = edge-type transform ---------
__global__ void eet_kernel(const float* __restrict__ edge_emb, const float* __restrict__ We_l,
                           const int* __restrict__ counts, float* __restrict__ eet) {
    int hc = threadIdx.x;  // 256
    float inv = 1.f / (float)E_EDGES;
    for (int t = 0; t < 3; ++t) {
        float acc = 0.f;
#pragma unroll
        for (int d = 0; d < EDGE_DIM; ++d) acc += edge_emb[t * EDGE_DIM + d] * We_l[d * HH + hc];
        eet[t * HH + hc] = acc;
    }
    float acc = 0.f;
#pragma unroll
    for (int d = 0; d < EDGE_DIM; ++d) {
        float md = (counts[0] * edge_emb[0 * EDGE_DIM + d] +
                    counts[1] * edge_emb[1 * EDGE_DIM + d] +
                    counts[2] * edge_emb[2 * EDGE_DIM + d]) * inv;
        acc += md * We_l[d * HH + hc];
    }
    eet[3 * HH + hc] = acc;
}

// ---------------- Kernel 4: xl = x@Wl, xr = x@Wr (bf16 out) ----------
// 16 nodes per block, 256 threads = one output column (of 256) each.
__global__ void transform_kernel(const float* __restrict__ x, const float* __restrict__ Wl,
                                 const float* __restrict__ Wr, unsigned short* __restrict__ xl,
                                 unsigned short* __restrict__ xr) {
    int base = blockIdx.x * 16;
    int hc = threadIdx.x;  // 256
    __shared__ float xs[16][HID];
    for (int i = threadIdx.x; i < 16 * HID; i += 256) {
        int r = i >> 6, k = i & 63;
        xs[r][k] = x[(size_t)(base + r) * HID + k];
    }
    __syncthreads();
    float al[16], ar[16];
#pragma unroll
    for (int i = 0; i < 16; ++i) { al[i] = 0.f; ar[i] = 0.f; }
    for (int k0 = 0; k0 < HID; k0 += 4) {
        float wl0 = Wl[(k0 + 0) * HH + hc], wr0 = Wr[(k0 + 0) * HH + hc];
        float wl1 = Wl[(k0 + 1) * HH + hc], wr1 = Wr[(k0 + 1) * HH + hc];
        float wl2 = Wl[(k0 + 2) * HH + hc], wr2 = Wr[(k0 + 2) * HH + hc];
        float wl3 = Wl[(k0 + 3) * HH + hc], wr3 = Wr[(k0 + 3) * HH + hc];
#pragma unroll
        for (int i = 0; i < 16; ++i) {
            float4 xv = *(const float4*)&xs[i][k0];
            al[i] += xv.x * wl0 + xv.y * wl1 + xv.z * wl2 + xv.w * wl3;
            ar[i] += xv.x * wr0 + xv.y * wr1 + xv.z * wr2 + xv.w * wr3;
        }
    }
#pragma unroll
    for (int i = 0; i < 16; ++i) {
        xl[(size_t)(base + i) * HH + hc] = f2bf(al[i]);
        xr[(size_t)(base + i) * HH + hc] = f2bf(ar[i]);
    }
}

// ---------------- Kernel 5: per-edge score -> a=exp(s), denom --------
// No segment-max: |s| <= ~2 so exp(s) is numerically safe and alpha is
// mathematically identical to exp(s - smax)/sum.
__global__ void score_kernel(const int* __restrict__ src_idx, const int* __restrict__ dst_idx,
                             const int* __restrict__ attr, const unsigned short* __restrict__ xl,
                             const unsigned short* __restrict__ xr, const float* __restrict__ eet,
                             const float* __restrict__ att_l, float* __restrict__ a_out,
                             float* __restrict__ denom) {
    int e = blockIdx.x * 4 + (threadIdx.x >> 6);
    if (e >= EA) return;
    int lane = threadIdx.x & 63;
    int srcn, dstn, t;
    if (e < E_EDGES) { srcn = src_idx[e]; dstn = dst_idx[e]; t = attr[e]; }
    else             { srcn = e - E_EDGES; dstn = srcn; t = 3; }
    const ushort4 xv = *(const ushort4*)(xl + (size_t)srcn * HH + lane * 4);
    const ushort4 rv = *(const ushort4*)(xr + (size_t)dstn * HH + lane * 4);
    const float4  ev = *(const float4*)(eet + t * HH + lane * 4);
    const float4  av = *(const float4*)(att_l + lane * 4);
    float m0 = bf2f(xv.x) + bf2f(rv.x) + ev.x;
    float m1 = bf2f(xv.y) + bf2f(rv.y) + ev.y;
    float m2 = bf2f(xv.z) + bf2f(rv.z) + ev.z;
    float m3 = bf2f(xv.w) + bf2f(rv.w) + ev.w;
    m0 = (m0 >= 0.f) ? m0 : NEG_SLOPE * m0;
    m1 = (m1 >= 0.f) ? m1 : NEG_SLOPE * m1;
    m2 = (m2 >= 0.f) ? m2 : NEG_SLOPE * m2;
    m3 = (m3 >= 0.f) ? m3 : NEG_SLOPE * m3;
    float p = m0 * av.x + m1 * av.y + m2 * av.z + m3 * av.w;
    // lanes 16h..16h+15 all belong to head h -> reduce within 16-lane groups
    for (int o = 1; o < 16; o <<= 1) p += __shfl_xor(p, o);
    if ((lane & 15) == 0) {
        int h = lane >> 4;
        float a = __expf(p);
        a_out[(size_t)e * 4 + h] = a;
        atomicAdd(&denom[dstn * 4 + h], a);
    }
}

// ---------------- Kernel 6: out[dst] += mean_h alpha_h * xl[src,h,:] -
__global__ void aggregate_kernel(const int* __restrict__ src_idx, const int* __restrict__ dst_idx,
                                 const float* __restrict__ a, const float* __restrict__ denom,
                                 const unsigned short* __restrict__ xl, float* __restrict__ outacc) {
    int e = blockIdx.x * 4 + (threadIdx.x >> 6);
    if (e >= EA) return;
    int lane = threadIdx.x & 63;
    int srcn, dstn;
    if (e < E_EDGES) { srcn = src_idx[e]; dstn = dst_idx[e]; }
    else             { srcn = e - E_EDGES; dstn = srcn; }
    float al0 = a[(size_t)e * 4 + 0] / denom[dstn * 4 + 0];
    float al1 = a[(size_t)e * 4 + 1] / denom[dstn * 4 + 1];
    float al2 = a[(size_t)e * 4 + 2] / denom[dstn * 4 + 2];
    float al3 = a[(size_t)e * 4 + 3] / denom[dstn * 4 + 3];
    const unsigned short* xp = xl + (size_t)srcn * HH;
    float v = 0.25f * (al0 * bf2f(xp[lane]) + al1 * bf2f(xp[64 + lane]) +
                       al2 * bf2f(xp[128 + lane]) + al3 * bf2f(xp[192 + lane]));
    atomicAdd(&outacc[(size_t)dstn * HID + lane], v);
}

// ---------------- Kernel 7: residual + LayerNorm ---------------------
__global__ void ln_kernel(const float* __restrict__ outacc, const float* __restrict__ bias_l,
                          const float* __restrict__ ln_w, const float* __restrict__ ln_b,
                          const float* __restrict__ x_in, float* __restrict__ x_out) {
    int n = blockIdx.x * 4 + (threadIdx.x >> 6);
    if (n >= N_NODES) return;
    int c = threadIdx.x & 63;
    float h = outacc[(size_t)n * HID + c] + bias_l[c] + x_in[(size_t)n * HID + c];
    float sum = h;
    for (int o = 32; o; o >>= 1) sum += __shfl_xor(sum, o);
    float mu = sum * (1.f / 64.f);
    float d = h - mu;
    float vs = d * d;
    for (int o = 32; o; o >>= 1) vs += __shfl_xor(vs, o);
    float var = vs * (1.f / 64.f);
    x_out[(size_t)n * HID + c] = d * rsqrtf(var + 1e-5f) * ln_w[c] + ln_b[c];
}

extern "C" void kernel_launch(void* const* d_in, const int* in_sizes, int n_in,
                              void* d_out, int out_size, void* d_ws, size_t ws_size,
                              hipStream_t stream) {
    const float* x_in     = (const float*)d_in[0];
    const int*   edge_idx = (const int*)d_in[1];   // [2, E]: row0 = src, row1 = dst
    const int*   attr     = (const int*)d_in[2];
    const float* proj_w   = (const float*)d_in[3];
    const float* proj_b   = (const float*)d_in[4];
    const float* edge_emb = (const float*)d_in[5];
    const float* Wl       = (const float*)d_in[6];
    const float* Wr       = (const float*)d_in[7];
    const float* We       = (const float*)d_in[8];
    const float* att      = (const float*)d_in[9];
    const float* bias     = (const float*)d_in[10];
    const float* ln_w     = (const float*)d_in[11];
    const float* ln_b     = (const float*)d_in[12];
    float* out = (float*)d_out;

    const int* src_idx = edge_idx;
    const int* dst_idx = edge_idx + E_EDGES;

    // Workspace layout
    float* ws = (float*)d_ws;
    float* x_cur  = ws;                                        // N*HID floats
    unsigned short* xl_bf = (unsigned short*)(x_cur + (size_t)N_NODES * HID);  // N*HH u16
    unsigned short* xr_bf = xl_bf + (size_t)N_NODES * HH;                      // N*HH u16
    float* a_buf  = (float*)(xr_bf + (size_t)N_NODES * HH);    // EA*4 floats
    float* outacc = a_buf + (size_t)EA * 4;                    // N*HID floats
    float* denom  = outacc + (size_t)N_NODES * HID;            // N*4 floats
    float* eet    = denom + (size_t)N_NODES * 4;               // 4*HH floats
    int*   counts = (int*)(eet + 4 * HH);                      // 4 ints

    hipMemsetAsync(counts, 0, 4 * sizeof(int), stream);
    proj_kernel<<<N_NODES / 16, 256, 0, stream>>>(x_in, proj_w, proj_b, x_cur);
    count_attr_kernel<<<256, 256, 0, stream>>>(attr, counts);

    for (int l = 0; l < L_LAYERS; ++l) {
        const float* Wl_l = Wl + (size_t)l * HID * HH;
        const float* Wr_l = Wr + (size_t)l * HID * HH;
        const float* We_l = We + (size_t)l * EDGE_DIM * HH;
        const float* att_l = att + (size_t)l * HH;
        const float* bias_l = bias + (size_t)l * HID;
        const float* lnw_l = ln_w + (size_t)l * HID;
        const float* lnb_l = ln_b + (size_t)l * HID;

        eet_kernel<<<1, 256, 0, stream>>>(edge_emb, We_l, counts, eet);
        transform_kernel<<<N_NODES / 16, 256, 0, stream>>>(x_cur, Wl_l, Wr_l, xl_bf, xr_bf);

        hipMemsetAsync(denom, 0, (size_t)N_NODES * 4 * sizeof(float), stream);
        hipMemsetAsync(outacc, 0, (size_t)N_NODES * HID * sizeof(float), stream);

        score_kernel<<<(EA + 3) / 4, 256, 0, stream>>>(src_idx, dst_idx, attr, xl_bf, xr_bf, eet,
                                                       att_l, a_buf, denom);
        aggregate_kernel<<<(EA + 3) / 4, 256, 0, stream>>>(src_idx, dst_idx, a_buf, denom, xl_bf, outacc);

        float* x_next = (l == L_LAYERS - 1) ? out : x_cur;
        ln_kernel<<<(N_NODES + 3) / 4, 256, 0, stream>>>(outacc, bias_l, lnw_l, lnb_l, x_cur, x_next);
    }
}

// Round 3
// 492.805 us; speedup vs baseline: 3.0358x; 1.9865x over previous
//
#include <hip/hip_runtime.h>

// Problem constants
constexpr int N_NODES = 50000;
constexpr int E_EDGES = 800000;
constexpr int EA      = E_EDGES + N_NODES;  // edges + self loops
constexpr int IN_DIM  = 128;
constexpr int HID     = 64;
constexpr int HEADS   = 4;
constexpr int HH      = HEADS * HID;        // 256
constexpr int EDGE_DIM = 8;
constexpr int L_LAYERS = 2;
constexpr float NEG_SLOPE = 0.2f;
constexpr int NB_SCAN = (N_NODES + 255) / 256;  // 196

__device__ __forceinline__ unsigned short f2bf(float f) {
    unsigned int b = __float_as_uint(f);
    unsigned int r = (b + 0x7FFFu + ((b >> 16) & 1u)) >> 16;  // RNE
    return (unsigned short)r;
}
__device__ __forceinline__ float bf2f(unsigned short u) {
    return __uint_as_float(((unsigned int)u) << 16);
}
__device__ __forceinline__ float lrelu(float x) { return x >= 0.f ? x : NEG_SLOPE * x; }

// ---------------- Kernel 1: x = x_in @ proj_w + proj_b ----------------
__global__ void proj_kernel(const float* __restrict__ x, const float* __restrict__ w,
                            const float* __restrict__ b, float* __restrict__ out) {
    int base = blockIdx.x * 16;
    int c = threadIdx.x & 63;
    int g = threadIdx.x >> 6;  // 0..3
    __shared__ float xs[16][IN_DIM];
    for (int i = threadIdx.x; i < 16 * IN_DIM; i += 256) {
        int r = i >> 7, k = i & 127;
        xs[r][k] = x[(size_t)(base + r) * IN_DIM + k];
    }
    __syncthreads();
    float acc[4];
    float bc = b[c];
#pragma unroll
    for (int j = 0; j < 4; ++j) acc[j] = bc;
    for (int k0 = 0; k0 < IN_DIM; k0 += 4) {
        float w0 = w[(k0 + 0) * HID + c];
        float w1 = w[(k0 + 1) * HID + c];
        float w2 = w[(k0 + 2) * HID + c];
        float w3 = w[(k0 + 3) * HID + c];
#pragma unroll
        for (int j = 0; j < 4; ++j) {
            float4 xv = *(const float4*)&xs[g + 4 * j][k0];
            acc[j] += xv.x * w0 + xv.y * w1 + xv.z * w2 + xv.w * w3;
        }
    }
#pragma unroll
    for (int j = 0; j < 4; ++j) out[(size_t)(base + g + 4 * j) * HID + c] = acc[j];
}

// ---------------- edge-attr histogram (for mean edge feature) --------
__global__ void count_attr_kernel(const int* __restrict__ attr, int* __restrict__ counts) {
    int c0 = 0, c1 = 0, c2 = 0;
    for (int i = blockIdx.x * blockDim.x + threadIdx.x; i < E_EDGES; i += gridDim.x * blockDim.x) {
        int a = attr[i];
        c0 += (a == 0); c1 += (a == 1); c2 += (a == 2);
    }
    for (int o = 32; o; o >>= 1) {
        c0 += __shfl_down(c0, o);
        c1 += __shfl_down(c1, o);
        c2 += __shfl_down(c2, o);
    }
    if ((threadIdx.x & 63) == 0) {
        atomicAdd(&counts[0], c0);
        atomicAdd(&counts[1], c1);
        atomicAdd(&counts[2], c2);
    }
}

// ---------------- eet[t][hc] = edge-type transform -------------------
__global__ void eet_kernel(const float* __restrict__ edge_emb, const float* __restrict__ We_l,
                           const int* __restrict__ counts, float* __restrict__ eet) {
    int hc = threadIdx.x;  // 256
    float inv = 1.f / (float)E_EDGES;
    for (int t = 0; t < 3; ++t) {
        float acc = 0.f;
#pragma unroll
        for (int d = 0; d < EDGE_DIM; ++d) acc += edge_emb[t * EDGE_DIM + d] * We_l[d * HH + hc];
        eet[t * HH + hc] = acc;
    }
    float acc = 0.f;
#pragma unroll
    for (int d = 0; d < EDGE_DIM; ++d) {
        float md = (counts[0] * edge_emb[0 * EDGE_DIM + d] +
                    counts[1] * edge_emb[1 * EDGE_DIM + d] +
                    counts[2] * edge_emb[2 * EDGE_DIM + d]) * inv;
        acc += md * We_l[d * HH + hc];
    }
    eet[3 * HH + hc] = acc;
}

// ---------------- CSR build: histogram of dst ------------------------
__global__ void hist_kernel(const int* __restrict__ dst, int* __restrict__ deg) {
    int e = blockIdx.x * 256 + threadIdx.x;
    if (e >= E_EDGES) return;
    atomicAdd(&deg[dst[e]], 1);
}

// scan level 1: per-256 block exclusive scan of (deg+1), block sums out
__global__ void scan1_kernel(const int* __restrict__ deg, int* __restrict__ loc,
                             int* __restrict__ sums) {
    __shared__ int s[256];
    int i = blockIdx.x * 256 + threadIdx.x;
    int v = (i < N_NODES) ? (deg[i] + 1) : 0;
    s[threadIdx.x] = v;
    __syncthreads();
    for (int o = 1; o < 256; o <<= 1) {
        int t = (threadIdx.x >= o) ? s[threadIdx.x - o] : 0;
        __syncthreads();
        s[threadIdx.x] += t;
        __syncthreads();
    }
    if (i < N_NODES) loc[i] = s[threadIdx.x] - v;
    if (threadIdx.x == 255) sums[blockIdx.x] = s[255];
}

// scan level 2: exclusive scan of block sums (NB_SCAN <= 256), single block
__global__ void scan2_kernel(int* __restrict__ sums) {
    __shared__ int s[256];
    int v = (threadIdx.x < NB_SCAN) ? sums[threadIdx.x] : 0;
    s[threadIdx.x] = v;
    __syncthreads();
    for (int o = 1; o < 256; o <<= 1) {
        int t = (threadIdx.x >= o) ? s[threadIdx.x - o] : 0;
        __syncthreads();
        s[threadIdx.x] += t;
        __syncthreads();
    }
    if (threadIdx.x < NB_SCAN) sums[threadIdx.x] = s[threadIdx.x] - v;
}

// finalize: offsets, self-loop entry, fill cursor
__global__ void finalize_kernel(const int* __restrict__ loc, const int* __restrict__ sums,
                                int* __restrict__ offsets, int* __restrict__ fill,
                                unsigned int* __restrict__ csr) {
    int n = blockIdx.x * 256 + threadIdx.x;
    if (n >= N_NODES) return;
    int off = loc[n] + sums[n >> 8];
    offsets[n] = off;
    csr[off] = (unsigned int)n | (3u << 16);  // self-loop, type 3 (mean edge feat)
    fill[n] = off + 1;
}

// scatter edges into CSR (src fits in 16 bits since N < 65536)
__global__ void scatter_kernel(const int* __restrict__ src, const int* __restrict__ dst,
                               const int* __restrict__ attr, int* __restrict__ fill,
                               unsigned int* __restrict__ csr) {
    int e = blockIdx.x * 256 + threadIdx.x;
    if (e >= E_EDGES) return;
    int d = dst[e];
    int pos = atomicAdd(&fill[d], 1);
    csr[pos] = (unsigned int)src[e] | ((unsigned int)attr[e] << 16);
}

// ---------------- xl = x@Wl, xr = x@Wr (bf16 out) --------------------
__global__ void transform_kernel(const float* __restrict__ x, const float* __restrict__ Wl,
                                 const float* __restrict__ Wr, unsigned short* __restrict__ xl,
                                 unsigned short* __restrict__ xr) {
    int base = blockIdx.x * 16;
    int hc = threadIdx.x;  // 256
    __shared__ float xs[16][HID];
    for (int i = threadIdx.x; i < 16 * HID; i += 256) {
        int r = i >> 6, k = i & 63;
        xs[r][k] = x[(size_t)(base + r) * HID + k];
    }
    __syncthreads();
    float al[16], ar[16];
#pragma unroll
    for (int i = 0; i < 16; ++i) { al[i] = 0.f; ar[i] = 0.f; }
    for (int k0 = 0; k0 < HID; k0 += 4) {
        float wl0 = Wl[(k0 + 0) * HH + hc], wr0 = Wr[(k0 + 0) * HH + hc];
        float wl1 = Wl[(k0 + 1) * HH + hc], wr1 = Wr[(k0 + 1) * HH + hc];
        float wl2 = Wl[(k0 + 2) * HH + hc], wr2 = Wr[(k0 + 2) * HH + hc];
        float wl3 = Wl[(k0 + 3) * HH + hc], wr3 = Wr[(k0 + 3) * HH + hc];
#pragma unroll
        for (int i = 0; i < 16; ++i) {
            float4 xv = *(const float4*)&xs[i][k0];
            al[i] += xv.x * wl0 + xv.y * wl1 + xv.z * wl2 + xv.w * wl3;
            ar[i] += xv.x * wr0 + xv.y * wr1 + xv.z * wr2 + xv.w * wr3;
        }
    }
#pragma unroll
    for (int i = 0; i < 16; ++i) {
        xl[(size_t)(base + i) * HH + hc] = f2bf(al[i]);
        xr[(size_t)(base + i) * HH + hc] = f2bf(ar[i]);
    }
}

// ---------------- Fused GAT: score + softmax + aggregate + LN --------
// One wave per dst node. Lane owns channels hc = 4*lane..4*lane+3 (head = lane>>4).
__global__ void gat_fused_kernel(const unsigned int* __restrict__ csr,
                                 const int* __restrict__ offsets, const int* __restrict__ deg,
                                 const unsigned short* __restrict__ xl,
                                 const unsigned short* __restrict__ xr,
                                 const float* __restrict__ eet, const float* __restrict__ att_l,
                                 const float* __restrict__ bias_l, const float* __restrict__ lnw,
                                 const float* __restrict__ lnb, const float* __restrict__ x_res,
                                 float* __restrict__ x_out) {
    __shared__ float4 eetS[256];  // [4 types][64 lanes] float4
    eetS[threadIdx.x] = ((const float4*)eet)[threadIdx.x];
    __syncthreads();
    int n = blockIdx.x * 4 + (threadIdx.x >> 6);  // N divisible by 4
    int lane = threadIdx.x & 63;
    float4 av = *(const float4*)(att_l + lane * 4);
    ushort4 xrv = *(const ushort4*)(xr + (size_t)n * HH + lane * 4);
    float xr0 = bf2f(xrv.x), xr1 = bf2f(xrv.y), xr2 = bf2f(xrv.z), xr3 = bf2f(xrv.w);
    int beg = offsets[n];
    int cnt = deg[n] + 1;
    float acc0 = 0.f, acc1 = 0.f, acc2 = 0.f, acc3 = 0.f, den = 0.f;
    int i = 0;
    for (; i + 2 <= cnt; i += 2) {
        unsigned int e0 = csr[beg + i], e1 = csr[beg + i + 1];
        int s0 = e0 & 0xFFFFu, t0 = e0 >> 16;
        int s1 = e1 & 0xFFFFu, t1 = e1 >> 16;
        ushort4 xv0 = *(const ushort4*)(xl + (size_t)s0 * HH + lane * 4);
        ushort4 xv1 = *(const ushort4*)(xl + (size_t)s1 * HH + lane * 4);
        float4 ee0 = eetS[t0 * 64 + lane];
        float4 ee1 = eetS[t1 * 64 + lane];
        float a0_ = bf2f(xv0.x), a1_ = bf2f(xv0.y), a2_ = bf2f(xv0.z), a3_ = bf2f(xv0.w);
        float b0_ = bf2f(xv1.x), b1_ = bf2f(xv1.y), b2_ = bf2f(xv1.z), b3_ = bf2f(xv1.w);
        float p0 = lrelu(a0_ + xr0 + ee0.x) * av.x + lrelu(a1_ + xr1 + ee0.y) * av.y +
                   lrelu(a2_ + xr2 + ee0.z) * av.z + lrelu(a3_ + xr3 + ee0.w) * av.w;
        float p1 = lrelu(b0_ + xr0 + ee1.x) * av.x + lrelu(b1_ + xr1 + ee1.y) * av.y +
                   lrelu(b2_ + xr2 + ee1.z) * av.z + lrelu(b3_ + xr3 + ee1.w) * av.w;
        p0 += __shfl_xor(p0, 1); p1 += __shfl_xor(p1, 1);
        p0 += __shfl_xor(p0, 2); p1 += __shfl_xor(p1, 2);
        p0 += __shfl_xor(p0, 4); p1 += __shfl_xor(p1, 4);
        p0 += __shfl_xor(p0, 8); p1 += __shfl_xor(p1, 8);
        float w0 = __expf(p0), w1 = __expf(p1);
        den += w0 + w1;
        acc0 += w0 * a0_ + w1 * b0_;
        acc1 += w0 * a1_ + w1 * b1_;
        acc2 += w0 * a2_ + w1 * b2_;
        acc3 += w0 * a3_ + w1 * b3_;
    }
    if (i < cnt) {
        unsigned int e0 = csr[beg + i];
        int s0 = e0 & 0xFFFFu, t0 = e0 >> 16;
        ushort4 xv0 = *(const ushort4*)(xl + (size_t)s0 * HH + lane * 4);
        float4 ee0 = eetS[t0 * 64 + lane];
        float a0_ = bf2f(xv0.x), a1_ = bf2f(xv0.y), a2_ = bf2f(xv0.z), a3_ = bf2f(xv0.w);
        float p0 = lrelu(a0_ + xr0 + ee0.x) * av.x + lrelu(a1_ + xr1 + ee0.y) * av.y +
                   lrelu(a2_ + xr2 + ee0.z) * av.z + lrelu(a3_ + xr3 + ee0.w) * av.w;
        p0 += __shfl_xor(p0, 1);
        p0 += __shfl_xor(p0, 2);
        p0 += __shfl_xor(p0, 4);
        p0 += __shfl_xor(p0, 8);
        float w0 = __expf(p0);
        den += w0;
        acc0 += w0 * a0_; acc1 += w0 * a1_; acc2 += w0 * a2_; acc3 += w0 * a3_;
    }
    // alpha-normalize, then sum across heads (lanes differing in bits 4,5)
    float inv = 1.f / den;
    float r0 = acc0 * inv, r1 = acc1 * inv, r2 = acc2 * inv, r3 = acc3 * inv;
    r0 += __shfl_xor(r0, 16); r1 += __shfl_xor(r1, 16);
    r2 += __shfl_xor(r2, 16); r3 += __shfl_xor(r3, 16);
    r0 += __shfl_xor(r0, 32); r1 += __shfl_xor(r1, 32);
    r2 += __shfl_xor(r2, 32); r3 += __shfl_xor(r3, 32);
    // lanes 0..15: bias + residual + LayerNorm over 64 channels, c = 4*lane+j
    if (lane < 16) {
        float4 xc = *(const float4*)(x_res + (size_t)n * HID + lane * 4);
        float4 bb = *(const float4*)(bias_l + lane * 4);
        float h0 = 0.25f * r0 + bb.x + xc.x;
        float h1 = 0.25f * r1 + bb.y + xc.y;
        float h2 = 0.25f * r2 + bb.z + xc.z;
        float h3 = 0.25f * r3 + bb.w + xc.w;
        float sum = h0 + h1 + h2 + h3;
        sum += __shfl_xor(sum, 1); sum += __shfl_xor(sum, 2);
        sum += __shfl_xor(sum, 4); sum += __shfl_xor(sum, 8);
        float mu = sum * (1.f / 64.f);
        float d0 = h0 - mu, d1 = h1 - mu, d2 = h2 - mu, d3 = h3 - mu;
        float vs = d0 * d0 + d1 * d1 + d2 * d2 + d3 * d3;
        vs += __shfl_xor(vs, 1); vs += __shfl_xor(vs, 2);
        vs += __shfl_xor(vs, 4); vs += __shfl_xor(vs, 8);
        float rstd = rsqrtf(vs * (1.f / 64.f) + 1e-5f);
        float4 w4 = *(const float4*)(lnw + lane * 4);
        float4 b4 = *(const float4*)(lnb + lane * 4);
        float4 o;
        o.x = d0 * rstd * w4.x + b4.x;
        o.y = d1 * rstd * w4.y + b4.y;
        o.z = d2 * rstd * w4.z + b4.z;
        o.w = d3 * rstd * w4.w + b4.w;
        *(float4*)(x_out + (size_t)n * HID + lane * 4) = o;
    }
}

extern "C" void kernel_launch(void* const* d_in, const int* in_sizes, int n_in,
                              void* d_out, int out_size, void* d_ws, size_t ws_size,
                              hipStream_t stream) {
    const float* x_in     = (const float*)d_in[0];
    const int*   edge_idx = (const int*)d_in[1];
    const int*   attr     = (const int*)d_in[2];
    const float* proj_w   = (const float*)d_in[3];
    const float* proj_b   = (const float*)d_in[4];
    const float* edge_emb = (const float*)d_in[5];
    const float* Wl       = (const float*)d_in[6];
    const float* Wr       = (const float*)d_in[7];
    const float* We       = (const float*)d_in[8];
    const float* att      = (const float*)d_in[9];
    const float* bias     = (const float*)d_in[10];
    const float* ln_w     = (const float*)d_in[11];
    const float* ln_b     = (const float*)d_in[12];
    float* out = (float*)d_out;

    const int* src_idx = edge_idx;
    const int* dst_idx = edge_idx + E_EDGES;

    // Workspace layout
    float* ws = (float*)d_ws;
    float* x0 = ws;                                            // N*HID
    float* x1 = x0 + (size_t)N_NODES * HID;                    // N*HID
    unsigned short* xl_bf = (unsigned short*)(x1 + (size_t)N_NODES * HID);  // N*HH
    unsigned short* xr_bf = xl_bf + (size_t)N_NODES * HH;                   // N*HH
    unsigned int* csr = (unsigned int*)(xr_bf + (size_t)N_NODES * HH);      // EA
    int* offsets = (int*)(csr + EA);                           // N
    int* deg     = offsets + N_NODES;                          // N
    int* fill    = deg + N_NODES;                              // N
    int* loc     = fill + N_NODES;                             // N
    int* sums    = loc + N_NODES;                              // 256
    float* eet   = (float*)(sums + 256);                       // 4*HH
    int* counts  = (int*)(eet + 4 * HH);                       // 4

    hipMemsetAsync(deg, 0, (size_t)N_NODES * sizeof(int), stream);
    hipMemsetAsync(counts, 0, 4 * sizeof(int), stream);

    proj_kernel<<<N_NODES / 16, 256, 0, stream>>>(x_in, proj_w, proj_b, x0);
    count_attr_kernel<<<256, 256, 0, stream>>>(attr, counts);

    // CSR build (once; graph is layer-invariant)
    hist_kernel<<<(E_EDGES + 255) / 256, 256, 0, stream>>>(dst_idx, deg);
    scan1_kernel<<<NB_SCAN, 256, 0, stream>>>(deg, loc, sums);
    scan2_kernel<<<1, 256, 0, stream>>>(sums);
    finalize_kernel<<<NB_SCAN, 256, 0, stream>>>(loc, sums, offsets, fill, csr);
    scatter_kernel<<<(E_EDGES + 255) / 256, 256, 0, stream>>>(src_idx, dst_idx, attr, fill, csr);

    for (int l = 0; l < L_LAYERS; ++l) {
        const float* Wl_l = Wl + (size_t)l * HID * HH;
        const float* Wr_l = Wr + (size_t)l * HID * HH;
        const float* We_l = We + (size_t)l * EDGE_DIM * HH;
        const float* att_l = att + (size_t)l * HH;
        const float* bias_l = bias + (size_t)l * HID;
        const float* lnw_l = ln_w + (size_t)l * HID;
        const float* lnb_l = ln_b + (size_t)l * HID;

        const float* x_cur = (l == 0) ? x0 : x1;
        float* x_next = (l == L_LAYERS - 1) ? out : x1;

        eet_kernel<<<1, 256, 0, stream>>>(edge_emb, We_l, counts, eet);
        transform_kernel<<<N_NODES / 16, 256, 0, stream>>>(x_cur, Wl_l, Wr_l, xl_bf, xr_bf);
        gat_fused_kernel<<<N_NODES / 4, 256, 0, stream>>>(csr, offsets, deg, xl_bf, xr_bf, eet,
                                                          att_l, bias_l, lnw_l, lnb_l, x_cur, x_next);
    }
}

// Round 4
// 472.451 us; speedup vs baseline: 3.1666x; 1.0431x over previous
//
#include <hip/hip_runtime.h>

// Problem constants
constexpr int N_NODES = 50000;
constexpr int E_EDGES = 800000;
constexpr int EA      = E_EDGES + N_NODES;      // edges + self loops
constexpr int CSR_CAP = E_EDGES + 4 * N_NODES;  // padded-to-4 capacity
constexpr int IN_DIM  = 128;
constexpr int HID     = 64;
constexpr int HEADS   = 4;
constexpr int HH      = HEADS * HID;            // 256
constexpr int EDGE_DIM = 8;
constexpr int L_LAYERS = 2;
constexpr float NEG_SLOPE = 0.2f;
constexpr int NB_SCAN = (N_NODES + 255) / 256;  // 196

__device__ __forceinline__ unsigned short f2bf(float f) {
    unsigned int b = __float_as_uint(f);
    unsigned int r = (b + 0x7FFFu + ((b >> 16) & 1u)) >> 16;  // RNE
    return (unsigned short)r;
}
__device__ __forceinline__ float bf2f(unsigned short u) {
    return __uint_as_float(((unsigned int)u) << 16);
}
__device__ __forceinline__ float lrelu(float x) { return fmaxf(x, NEG_SLOPE * x); }

// ---------------- x = x_in @ proj_w + proj_b -------------------------
__global__ void proj_kernel(const float* __restrict__ x, const float* __restrict__ w,
                            const float* __restrict__ b, float* __restrict__ out) {
    int base = blockIdx.x * 16;
    int c = threadIdx.x & 63;
    int g = threadIdx.x >> 6;  // 0..3
    __shared__ float xs[16][IN_DIM];
    for (int i = threadIdx.x; i < 16 * IN_DIM; i += 256) {
        int r = i >> 7, k = i & 127;
        xs[r][k] = x[(size_t)(base + r) * IN_DIM + k];
    }
    __syncthreads();
    float acc[4];
    float bc = b[c];
#pragma unroll
    for (int j = 0; j < 4; ++j) acc[j] = bc;
    for (int k0 = 0; k0 < IN_DIM; k0 += 4) {
        float w0 = w[(k0 + 0) * HID + c];
        float w1 = w[(k0 + 1) * HID + c];
        float w2 = w[(k0 + 2) * HID + c];
        float w3 = w[(k0 + 3) * HID + c];
#pragma unroll
        for (int j = 0; j < 4; ++j) {
            float4 xv = *(const float4*)&xs[g + 4 * j][k0];
            acc[j] += xv.x * w0 + xv.y * w1 + xv.z * w2 + xv.w * w3;
        }
    }
#pragma unroll
    for (int j = 0; j < 4; ++j) out[(size_t)(base + g + 4 * j) * HID + c] = acc[j];
}

// ---------------- edge-attr histogram --------------------------------
__global__ void count_attr_kernel(const int* __restrict__ attr, int* __restrict__ counts) {
    int c0 = 0, c1 = 0, c2 = 0;
    for (int i = blockIdx.x * blockDim.x + threadIdx.x; i < E_EDGES; i += gridDim.x * blockDim.x) {
        int a = attr[i];
        c0 += (a == 0); c1 += (a == 1); c2 += (a == 2);
    }
    for (int o = 32; o; o >>= 1) {
        c0 += __shfl_down(c0, o);
        c1 += __shfl_down(c1, o);
        c2 += __shfl_down(c2, o);
    }
    if ((threadIdx.x & 63) == 0) {
        atomicAdd(&counts[0], c0);
        atomicAdd(&counts[1], c1);
        atomicAdd(&counts[2], c2);
    }
}

// ---------------- eet[l][t][hc] for BOTH layers ----------------------
__global__ void eet2_kernel(const float* __restrict__ edge_emb, const float* __restrict__ We,
                            const int* __restrict__ counts, float* __restrict__ eet) {
    int hc = threadIdx.x;  // 256
    float inv = 1.f / (float)E_EDGES;
    for (int l = 0; l < L_LAYERS; ++l) {
        const float* We_l = We + (size_t)l * EDGE_DIM * HH;
        float* eet_l = eet + (size_t)l * 4 * HH;
        for (int t = 0; t < 3; ++t) {
            float acc = 0.f;
#pragma unroll
            for (int d = 0; d < EDGE_DIM; ++d) acc += edge_emb[t * EDGE_DIM + d] * We_l[d * HH + hc];
            eet_l[t * HH + hc] = acc;
        }
        float acc = 0.f;
#pragma unroll
        for (int d = 0; d < EDGE_DIM; ++d) {
            float md = (counts[0] * edge_emb[0 * EDGE_DIM + d] +
                        counts[1] * edge_emb[1 * EDGE_DIM + d] +
                        counts[2] * edge_emb[2 * EDGE_DIM + d]) * inv;
            acc += md * We_l[d * HH + hc];
        }
        eet_l[3 * HH + hc] = acc;
    }
}

// ---------------- CSR build ------------------------------------------
__global__ void hist_kernel(const int* __restrict__ dst, int* __restrict__ deg) {
    int e = blockIdx.x * 256 + threadIdx.x;
    if (e >= E_EDGES) return;
    atomicAdd(&deg[dst[e]], 1);
}

// per-256 block exclusive scan of padded counts ((deg+1) rounded up to 4)
__global__ void scan1_kernel(const int* __restrict__ deg, int* __restrict__ loc,
                             int* __restrict__ sums) {
    __shared__ int s[256];
    int i = blockIdx.x * 256 + threadIdx.x;
    int v = (i < N_NODES) ? ((deg[i] + 4) & ~3) : 0;
    s[threadIdx.x] = v;
    __syncthreads();
    for (int o = 1; o < 256; o <<= 1) {
        int t = (threadIdx.x >= o) ? s[threadIdx.x - o] : 0;
        __syncthreads();
        s[threadIdx.x] += t;
        __syncthreads();
    }
    if (i < N_NODES) loc[i] = s[threadIdx.x] - v;
    if (threadIdx.x == 255) sums[blockIdx.x] = s[255];
}

__global__ void scan2_kernel(int* __restrict__ sums) {
    __shared__ int s[256];
    int v = (threadIdx.x < NB_SCAN) ? sums[threadIdx.x] : 0;
    s[threadIdx.x] = v;
    __syncthreads();
    for (int o = 1; o < 256; o <<= 1) {
        int t = (threadIdx.x >= o) ? s[threadIdx.x - o] : 0;
        __syncthreads();
        s[threadIdx.x] += t;
        __syncthreads();
    }
    if (threadIdx.x < NB_SCAN) sums[threadIdx.x] = s[threadIdx.x] - v;
}

// offsets (4-aligned), self-loop entry, padding dummies, fill cursor
__global__ void finalize_kernel(const int* __restrict__ loc, const int* __restrict__ sums,
                                const int* __restrict__ deg, int* __restrict__ offsets,
                                int* __restrict__ fill, unsigned int* __restrict__ csr) {
    int n = blockIdx.x * 256 + threadIdx.x;
    if (n >= N_NODES) return;
    int off = loc[n] + sums[n >> 8];
    offsets[n] = off;
    unsigned int selfe = (unsigned int)n | (3u << 16);  // type 3 = mean edge feat
    int cnt = deg[n] + 1;
    int pad = (cnt + 3) & ~3;
    csr[off] = selfe;
    for (int p = cnt; p < pad; ++p) csr[off + p] = selfe;  // masked dummies
    fill[n] = off + 1;
}

__global__ void scatter_kernel(const int* __restrict__ src, const int* __restrict__ dst,
                               const int* __restrict__ attr, int* __restrict__ fill,
                               unsigned int* __restrict__ csr) {
    int e = blockIdx.x * 256 + threadIdx.x;
    if (e >= E_EDGES) return;
    int d = dst[e];
    int pos = atomicAdd(&fill[d], 1);
    csr[pos] = (unsigned int)src[e] | ((unsigned int)attr[e] << 16);
}

// ---------------- xl = x@Wl, xr = x@Wr (bf16 out) --------------------
__global__ void transform_kernel(const float* __restrict__ x, const float* __restrict__ Wl,
                                 const float* __restrict__ Wr, unsigned short* __restrict__ xl,
                                 unsigned short* __restrict__ xr) {
    int base = blockIdx.x * 16;
    int hc = threadIdx.x;  // 256
    __shared__ float xs[16][HID];
    for (int i = threadIdx.x; i < 16 * HID; i += 256) {
        int r = i >> 6, k = i & 63;
        xs[r][k] = x[(size_t)(base + r) * HID + k];
    }
    __syncthreads();
    float al[16], ar[16];
#pragma unroll
    for (int i = 0; i < 16; ++i) { al[i] = 0.f; ar[i] = 0.f; }
    for (int k0 = 0; k0 < HID; k0 += 4) {
        float wl0 = Wl[(k0 + 0) * HH + hc], wr0 = Wr[(k0 + 0) * HH + hc];
        float wl1 = Wl[(k0 + 1) * HH + hc], wr1 = Wr[(k0 + 1) * HH + hc];
        float wl2 = Wl[(k0 + 2) * HH + hc], wr2 = Wr[(k0 + 2) * HH + hc];
        float wl3 = Wl[(k0 + 3) * HH + hc], wr3 = Wr[(k0 + 3) * HH + hc];
#pragma unroll
        for (int i = 0; i < 16; ++i) {
            float4 xv = *(const float4*)&xs[i][k0];
            al[i] += xv.x * wl0 + xv.y * wl1 + xv.z * wl2 + xv.w * wl3;
            ar[i] += xv.x * wr0 + xv.y * wr1 + xv.z * wr2 + xv.w * wr3;
        }
    }
#pragma unroll
    for (int i = 0; i < 16; ++i) {
        xl[(size_t)(base + i) * HH + hc] = f2bf(al[i]);
        xr[(size_t)(base + i) * HH + hc] = f2bf(ar[i]);
    }
}

// ---------------- Fused GAT: score + softmax + aggregate + LN --------
// One wave per dst node; 4 edges per iteration, all gathers independent.
__global__ void gat_fused_kernel(const unsigned int* __restrict__ csr,
                                 const int* __restrict__ offsets, const int* __restrict__ deg,
                                 const unsigned short* __restrict__ xl,
                                 const unsigned short* __restrict__ xr,
                                 const float* __restrict__ eet_l, const float* __restrict__ att_l,
                                 const float* __restrict__ bias_l, const float* __restrict__ lnw,
                                 const float* __restrict__ lnb, const float* __restrict__ x_res,
                                 float* __restrict__ x_out) {
    __shared__ float4 eetS[256];  // [4 types][64 lanes]
    eetS[threadIdx.x] = ((const float4*)eet_l)[threadIdx.x];
    __syncthreads();
    int n = blockIdx.x * 4 + (threadIdx.x >> 6);
    int lane = threadIdx.x & 63;
    float4 av = *(const float4*)(att_l + lane * 4);
    ushort4 xrv = *(const ushort4*)(xr + (size_t)n * HH + lane * 4);
    float xr0 = bf2f(xrv.x), xr1 = bf2f(xrv.y), xr2 = bf2f(xrv.z), xr3 = bf2f(xrv.w);
    int beg = offsets[n];
    int cnt = deg[n] + 1;
    int rounds = (cnt + 3) >> 2;
    const unsigned short* xlb = xl + lane * 4;  // per-lane channel base
    float accA0 = 0.f, accA1 = 0.f, accA2 = 0.f, accA3 = 0.f, denA = 0.f;
    float accB0 = 0.f, accB1 = 0.f, accB2 = 0.f, accB3 = 0.f, denB = 0.f;
    for (int it = 0; it < rounds; ++it) {
        uint4 ew = *(const uint4*)(csr + beg + (it << 2));
        int rem = cnt - (it << 2);  // #valid edges this round (>=1)
        int s0 = ew.x & 0xFFFFu, t0 = ew.x >> 16;
        int s1 = ew.y & 0xFFFFu, t1 = ew.y >> 16;
        int s2 = ew.z & 0xFFFFu, t2 = ew.z >> 16;
        int s3 = ew.w & 0xFFFFu, t3 = ew.w >> 16;
        ushort4 xv0 = *(const ushort4*)(xlb + (size_t)s0 * HH);
        ushort4 xv1 = *(const ushort4*)(xlb + (size_t)s1 * HH);
        ushort4 xv2 = *(const ushort4*)(xlb + (size_t)s2 * HH);
        ushort4 xv3 = *(const ushort4*)(xlb + (size_t)s3 * HH);
        float4 ee0 = eetS[(t0 << 6) + lane];
        float4 ee1 = eetS[(t1 << 6) + lane];
        float4 ee2 = eetS[(t2 << 6) + lane];
        float4 ee3 = eetS[(t3 << 6) + lane];
        float a0 = bf2f(xv0.x), a1 = bf2f(xv0.y), a2 = bf2f(xv0.z), a3 = bf2f(xv0.w);
        float b0 = bf2f(xv1.x), b1 = bf2f(xv1.y), b2 = bf2f(xv1.z), b3 = bf2f(xv1.w);
        float c0 = bf2f(xv2.x), c1 = bf2f(xv2.y), c2 = bf2f(xv2.z), c3 = bf2f(xv2.w);
        float d0 = bf2f(xv3.x), d1 = bf2f(xv3.y), d2 = bf2f(xv3.z), d3 = bf2f(xv3.w);
        float p0 = lrelu(a0 + xr0 + ee0.x) * av.x + lrelu(a1 + xr1 + ee0.y) * av.y +
                   lrelu(a2 + xr2 + ee0.z) * av.z + lrelu(a3 + xr3 + ee0.w) * av.w;
        float p1 = lrelu(b0 + xr0 + ee1.x) * av.x + lrelu(b1 + xr1 + ee1.y) * av.y +
                   lrelu(b2 + xr2 + ee1.z) * av.z + lrelu(b3 + xr3 + ee1.w) * av.w;
        float p2 = lrelu(c0 + xr0 + ee2.x) * av.x + lrelu(c1 + xr1 + ee2.y) * av.y +
                   lrelu(c2 + xr2 + ee2.z) * av.z + lrelu(c3 + xr3 + ee2.w) * av.w;
        float p3 = lrelu(d0 + xr0 + ee3.x) * av.x + lrelu(d1 + xr1 + ee3.y) * av.y +
                   lrelu(d2 + xr2 + ee3.z) * av.z + lrelu(d3 + xr3 + ee3.w) * av.w;
        p0 += __shfl_xor(p0, 1); p1 += __shfl_xor(p1, 1);
        p2 += __shfl_xor(p2, 1); p3 += __shfl_xor(p3, 1);
        p0 += __shfl_xor(p0, 2); p1 += __shfl_xor(p1, 2);
        p2 += __shfl_xor(p2, 2); p3 += __shfl_xor(p3, 2);
        p0 += __shfl_xor(p0, 4); p1 += __shfl_xor(p1, 4);
        p2 += __shfl_xor(p2, 4); p3 += __shfl_xor(p3, 4);
        p0 += __shfl_xor(p0, 8); p1 += __shfl_xor(p1, 8);
        p2 += __shfl_xor(p2, 8); p3 += __shfl_xor(p3, 8);
        float w0 = __expf(p0);
        float w1 = (rem > 1) ? __expf(p1) : 0.f;
        float w2 = (rem > 2) ? __expf(p2) : 0.f;
        float w3 = (rem > 3) ? __expf(p3) : 0.f;
        denA += w0 + w1;
        denB += w2 + w3;
        accA0 += w0 * a0 + w1 * b0;  accB0 += w2 * c0 + w3 * d0;
        accA1 += w0 * a1 + w1 * b1;  accB1 += w2 * c1 + w3 * d1;
        accA2 += w0 * a2 + w1 * b2;  accB2 += w2 * c2 + w3 * d2;
        accA3 += w0 * a3 + w1 * b3;  accB3 += w2 * c3 + w3 * d3;
    }
    float inv = 1.f / (denA + denB);
    float r0 = (accA0 + accB0) * inv, r1 = (accA1 + accB1) * inv;
    float r2 = (accA2 + accB2) * inv, r3 = (accA3 + accB3) * inv;
    // sum across heads (lanes differing in bits 4,5)
    r0 += __shfl_xor(r0, 16); r1 += __shfl_xor(r1, 16);
    r2 += __shfl_xor(r2, 16); r3 += __shfl_xor(r3, 16);
    r0 += __shfl_xor(r0, 32); r1 += __shfl_xor(r1, 32);
    r2 += __shfl_xor(r2, 32); r3 += __shfl_xor(r3, 32);
    if (lane < 16) {
        float4 xc = *(const float4*)(x_res + (size_t)n * HID + lane * 4);
        float4 bb = *(const float4*)(bias_l + lane * 4);
        float h0 = 0.25f * r0 + bb.x + xc.x;
        float h1 = 0.25f * r1 + bb.y + xc.y;
        float h2 = 0.25f * r2 + bb.z + xc.z;
        float h3 = 0.25f * r3 + bb.w + xc.w;
        float sum = h0 + h1 + h2 + h3;
        sum += __shfl_xor(sum, 1); sum += __shfl_xor(sum, 2);
        sum += __shfl_xor(sum, 4); sum += __shfl_xor(sum, 8);
        float mu = sum * (1.f / 64.f);
        float d0_ = h0 - mu, d1_ = h1 - mu, d2_ = h2 - mu, d3_ = h3 - mu;
        float vs = d0_ * d0_ + d1_ * d1_ + d2_ * d2_ + d3_ * d3_;
        vs += __shfl_xor(vs, 1); vs += __shfl_xor(vs, 2);
        vs += __shfl_xor(vs, 4); vs += __shfl_xor(vs, 8);
        float rstd = rsqrtf(vs * (1.f / 64.f) + 1e-5f);
        float4 w4 = *(const float4*)(lnw + lane * 4);
        float4 b4 = *(const float4*)(lnb + lane * 4);
        float4 o;
        o.x = d0_ * rstd * w4.x + b4.x;
        o.y = d1_ * rstd * w4.y + b4.y;
        o.z = d2_ * rstd * w4.z + b4.z;
        o.w = d3_ * rstd * w4.w + b4.w;
        *(float4*)(x_out + (size_t)n * HID + lane * 4) = o;
    }
}

extern "C" void kernel_launch(void* const* d_in, const int* in_sizes, int n_in,
                              void* d_out, int out_size, void* d_ws, size_t ws_size,
                              hipStream_t stream) {
    const float* x_in     = (const float*)d_in[0];
    const int*   edge_idx = (const int*)d_in[1];
    const int*   attr     = (const int*)d_in[2];
    const float* proj_w   = (const float*)d_in[3];
    const float* proj_b   = (const float*)d_in[4];
    const float* edge_emb = (const float*)d_in[5];
    const float* Wl       = (const float*)d_in[6];
    const float* Wr       = (const float*)d_in[7];
    const float* We       = (const float*)d_in[8];
    const float* att      = (const float*)d_in[9];
    const float* bias     = (const float*)d_in[10];
    const float* ln_w     = (const float*)d_in[11];
    const float* ln_b     = (const float*)d_in[12];
    float* out = (float*)d_out;

    const int* src_idx = edge_idx;
    const int* dst_idx = edge_idx + E_EDGES;

    // Workspace layout
    float* ws = (float*)d_ws;
    float* x0 = ws;                                            // N*HID
    float* x1 = x0 + (size_t)N_NODES * HID;                    // N*HID
    unsigned short* xl_bf = (unsigned short*)(x1 + (size_t)N_NODES * HID);  // N*HH
    unsigned short* xr_bf = xl_bf + (size_t)N_NODES * HH;                   // N*HH
    unsigned int* csr = (unsigned int*)(xr_bf + (size_t)N_NODES * HH);      // CSR_CAP
    int* offsets = (int*)(csr + CSR_CAP);                      // N
    int* deg     = offsets + N_NODES;                          // N
    int* fill    = deg + N_NODES;                              // N
    int* loc     = fill + N_NODES;                             // N
    int* sums    = loc + N_NODES;                              // 256
    float* eet   = (float*)(sums + 256);                       // L*4*HH
    int* counts  = (int*)(eet + L_LAYERS * 4 * HH);            // 4

    hipMemsetAsync(deg, 0, (size_t)N_NODES * sizeof(int), stream);
    hipMemsetAsync(counts, 0, 4 * sizeof(int), stream);

    proj_kernel<<<N_NODES / 16, 256, 0, stream>>>(x_in, proj_w, proj_b, x0);
    count_attr_kernel<<<256, 256, 0, stream>>>(attr, counts);

    // CSR build (once; graph is layer-invariant)
    hist_kernel<<<(E_EDGES + 255) / 256, 256, 0, stream>>>(dst_idx, deg);
    scan1_kernel<<<NB_SCAN, 256, 0, stream>>>(deg, loc, sums);
    scan2_kernel<<<1, 256, 0, stream>>>(sums);
    finalize_kernel<<<NB_SCAN, 256, 0, stream>>>(loc, sums, deg, offsets, fill, csr);
    scatter_kernel<<<(E_EDGES + 255) / 256, 256, 0, stream>>>(src_idx, dst_idx, attr, fill, csr);
    eet2_kernel<<<1, 256, 0, stream>>>(edge_emb, We, counts, eet);

    for (int l = 0; l < L_LAYERS; ++l) {
        const float* Wl_l = Wl + (size_t)l * HID * HH;
        const float* Wr_l = Wr + (size_t)l * HID * HH;
        const float* att_l = att + (size_t)l * HH;
        const float* bias_l = bias + (size_t)l * HID;
        const float* lnw_l = ln_w + (size_t)l * HID;
        const float* lnb_l = ln_b + (size_t)l * HID;
        const float* eet_l = eet + (size_t)l * 4 * HH;

        const float* x_cur = (l == 0) ? x0 : x1;
        float* x_next = (l == L_LAYERS - 1) ? out : x1;

        transform_kernel<<<N_NODES / 16, 256, 0, stream>>>(x_cur, Wl_l, Wr_l, xl_bf, xr_bf);
        gat_fused_kernel<<<N_NODES / 4, 256, 0, stream>>>(csr, offsets, deg, xl_bf, xr_bf, eet_l,
                                                          att_l, bias_l, lnw_l, lnb_l, x_cur, x_next);
    }
}